// Round 9
// baseline (198.275 us; speedup 1.0000x reference)
//
#include <hip/hip_runtime.h>
#include <math.h>

#define NELEC 10
#define NSPIN 2
#define NPER 5
#define DIM 3
#define NION 2
#define DP 32
#define NDENSE 64
#define NPERM 120
#define RS 324   // G row stride (words): the 5 selectable rows land on disjoint bank quads.
#define HTS 124  // HT row stride (words): phase-2 reads 8 b128 addrs spanning 32 consecutive
                 // words per wave -> all 32 banks once, conflict-free; phase-1 writes are
                 // consecutive-lane b32 -> 2 lanes/bank = free. 124%4==0 -> b128-aligned.

// tanh(x) = 1 - 2*rcp(exp(2x)+1): v_exp + v_rcp, ~1-2 ulp, exact at saturation. Validated R5-R8.
__device__ __forceinline__ float fast_tanh(float x) {
    float e = __expf(2.0f * x);
    return 1.0f - 2.0f * __builtin_amdgcn_rcpf(e + 1.0f);
}

__device__ __forceinline__ unsigned pick_remove(unsigned& el, int d) {
    unsigned v = (el >> (4 * d)) & 0xFu;
    unsigned low = el & ((1u << (4 * d)) - 1u);
    el = low | ((el >> (4 * (d + 1))) << (4 * d));
    return v;
}

// ---------------- main: one block per (batch, spin), 4 waves ----------------
// R8 (2-wave blocks) measured latency-bound: VALU 59%, occupancy 18% (= 2 waves/SIMD,
// LDS-limited to 4 blocks/CU). Same algorithm at 256 threads/block keeps LDS/block
// (and thus 4 blocks/CU) but doubles residency to 4 waves/SIMD. Phase-2 tile is now
// 4 perms x 8 j per lane -> still exactly 1 ds_read_b128 per k (LDS pipe ~20us stays
// under the ~26us VALU floor; an 8x4 tile would double LDS instrs -> LDS-bound).
__global__ __launch_bounds__(256, 1) void antisym_kern(
    const float* __restrict__ elec_pos, const float* __restrict__ ion_pos,
    const float* __restrict__ bf_w, const float* __restrict__ bf_b,
    const float* __restrict__ w0, const float* __restrict__ b0,
    const float* __restrict__ w1, const float* __restrict__ b1,
    const float* __restrict__ w2,
    float* __restrict__ psum, int B)
{
    const int b = blockIdx.x;
    const int s = blockIdx.y;
    const int t = threadIdx.x;
    const int wave = t >> 6, lane = t & 63;

    __shared__ float s1e[NPER * DP];                    // 640 B
    __shared__ __align__(16) float G[NPER][RS];         // 6480 B
    __shared__ __align__(16) float HT[NDENSE][HTS];     // 31744 B   HT[k][p] = h_p[k]
    __shared__ double red_h[2];
    __shared__ double red_j[4];                         // total ~38.9 KB -> 4 blocks/CU

    // ---- stage 1: stream_1e = tanh(feats @ bf_w + bf_b) for this spin's 5 electrons ----
    const float* ep = elec_pos + (b * NELEC + s * NPER) * DIM;
    const float i0x = ion_pos[0], i0y = ion_pos[1], i0z = ion_pos[2];
    const float i1x = ion_pos[3], i1y = ion_pos[4], i1z = ion_pos[5];
    for (int idx = t; idx < NPER * DP; idx += 256) {    // t < 160 active
        int j = idx >> 5, c = idx & 31;
        float ex = ep[j * 3 + 0], ey = ep[j * 3 + 1], ez = ep[j * 3 + 2];
        float dx0 = ex - i0x, dy0 = ey - i0y, dz0 = ez - i0z;
        float dx1 = ex - i1x, dy1 = ey - i1y, dz1 = ez - i1z;
        float n0 = sqrtf(dx0 * dx0 + dy0 * dy0 + dz0 * dz0);
        float n1 = sqrtf(dx1 * dx1 + dy1 * dy1 + dz1 * dz1);
        float acc = bf_b[c];
        acc += dx0 * bf_w[0 * DP + c];
        acc += dy0 * bf_w[1 * DP + c];
        acc += dz0 * bf_w[2 * DP + c];
        acc += dx1 * bf_w[3 * DP + c];
        acc += dy1 * bf_w[4 * DP + c];
        acc += dz1 * bf_w[5 * DP + c];
        acc += n0 * bf_w[6 * DP + c];
        acc += n1 * bf_w[7 * DP + c];
        s1e[idx] = fast_tanh(acc);
    }
    __syncthreads();

    // ---- stage 2: G[j][i*64+c] = s1e[j][:] @ w0[s][32i:32i+32, c] (validated body) ----
    const float* w0s = w0 + s * (NPER * DP) * NDENSE;   // [160][64]
    for (int j = wave; j < NPER; j += 4) {              // wave0: j=0,4; w1: 1; w2: 2; w3: 3
        float4 sv4[8];
        #pragma unroll
        for (int q = 0; q < 8; q++) sv4[q] = *(const float4*)(s1e + j * DP + q * 4);
        #pragma unroll
        for (int i = 0; i < NPER; i++) {
            float acc = 0.f;
            #pragma unroll
            for (int q = 0; q < 8; q++) {
                const float* wb = w0s + (i * DP + q * 4) * NDENSE + lane;  // coalesced
                acc += sv4[q].x * wb[0 * NDENSE];
                acc += sv4[q].y * wb[1 * NDENSE];
                acc += sv4[q].z * wb[2 * NDENSE];
                acc += sv4[q].w * wb[3 * NDENSE];
            }
            G[j][i * NDENSE + lane] = acc;
        }
    }
    __syncthreads();

    const float* b0s = b0 + s * NDENSE;
    const float* w2s = w2 + s * NDENSE;     // w2 is [s][64][1]

    // ---- stage 3 phase 1 (waves 0-1 only): perm t builds h_t -> HT; fold sign*hdot ----
    if (wave < 2) {
        float sign = 0.f;
        int p0 = 0, p1 = 0, p2 = 0, p3 = 0, p4 = 0;
        if (t < NPERM) {
            int p = t;
            unsigned el = 0x43210u;
            int d0 = p / 24; p -= d0 * 24;
            int d1 = p / 6;  p -= d1 * 6;
            int d2 = p / 2;  p -= d2 * 2;
            int d3 = p;
            p0 = pick_remove(el, d0);
            p1 = pick_remove(el, d1);
            p2 = pick_remove(el, d2);
            p3 = pick_remove(el, d3);
            p4 = el & 0xF;
            sign = ((d0 + d1 + d2 + d3) & 1) ? -1.f : 1.f;
        }
        const float* g0 = &G[p0][0 * NDENSE];
        const float* g1 = &G[p1][1 * NDENSE];
        const float* g2 = &G[p2][2 * NDENSE];
        const float* g3 = &G[p3][3 * NDENSE];
        const float* g4 = &G[p4][4 * NDENSE];

        float hdot = 0.f;
        #pragma unroll
        for (int cc = 0; cc < NDENSE / 4; cc++) {
            float4 a = *(const float4*)(b0s + cc * 4);                // uniform -> s_load
            float4 q;
            q = *(const float4*)(g0 + cc * 4); a.x += q.x; a.y += q.y; a.z += q.z; a.w += q.w;
            q = *(const float4*)(g1 + cc * 4); a.x += q.x; a.y += q.y; a.z += q.z; a.w += q.w;
            q = *(const float4*)(g2 + cc * 4); a.x += q.x; a.y += q.y; a.z += q.z; a.w += q.w;
            q = *(const float4*)(g3 + cc * 4); a.x += q.x; a.y += q.y; a.z += q.z; a.w += q.w;
            q = *(const float4*)(g4 + cc * 4); a.x += q.x; a.y += q.y; a.z += q.z; a.w += q.w;
            float t0 = fast_tanh(a.x), t1 = fast_tanh(a.y), t2 = fast_tanh(a.z), t3 = fast_tanh(a.w);
            if (t < NPERM) {                  // exec-masked conflict-free b32 writes
                HT[cc * 4 + 0][t] = t0;
                HT[cc * 4 + 1][t] = t1;
                HT[cc * 4 + 2][t] = t2;
                HT[cc * 4 + 3][t] = t3;
            }
            hdot += t0 * w2s[cc * 4 + 0] + t1 * w2s[cc * 4 + 1]
                  + t2 * w2s[cc * 4 + 2] + t3 * w2s[cc * 4 + 3];
        }
        double dvh = (double)(sign * hdot);   // sign=0 for t>=120
        #pragma unroll
        for (int off = 32; off > 0; off >>= 1) dvh += __shfl_down(dvh, off, 64);
        if (lane == 0) red_h[wave] = dvh;
    }
    __syncthreads();                          // HT visible to all 4 waves

    // ---- stage 3 phase 2: 4x8 register-tiled GEMM V[120x64] = H @ W1 ----
    const int pg = t >> 3;                    // 0..31; per wave, pb spans 32 consecutive words
    const int jg = t & 7;
    const bool pvalid = (pg < 30);            // pg 30,31 would be perms 120..127
    const int pb = pvalid ? 4 * pg : 0;
    const float* w1s = w1 + s * NDENSE * NDENSE;
    const float* b1s = b1 + s * NDENSE;
    const float* wgp = w1s + 8 * jg;          // this lane's j-octet in w1 row k

    float v[4][8];
    #pragma unroll
    for (int i = 0; i < 4; i++)
        #pragma unroll
        for (int r = 0; r < 8; r++) v[i][r] = 0.f;

    #pragma unroll 4
    for (int k = 0; k < NDENSE; k++) {
        float4 hq = *(const float4*)(&HT[k][pb]);          // 1 ds_read_b128, conflict-free
        float4 wa = *(const float4*)(wgp + k * NDENSE);    // global dwordx4, L1-hot
        float4 wb = *(const float4*)(wgp + k * NDENSE + 4);
        const float hv[4] = {hq.x, hq.y, hq.z, hq.w};
        const float wv[8] = {wa.x, wa.y, wa.z, wa.w, wb.x, wb.y, wb.z, wb.w};
        #pragma unroll
        for (int i = 0; i < 4; i++)
            #pragma unroll
            for (int r = 0; r < 8; r++)
                v[i][r] = fmaf(hv[i], wv[r], v[i][r]);
    }

    // epilogue: lanesum = sum_i sgn_i * sum_r tanh(v[i][r]+b1[j]) * w2[j]
    float4 b1a = *(const float4*)(b1s + 8 * jg);
    float4 b1b = *(const float4*)(b1s + 8 * jg + 4);
    float4 w2a = *(const float4*)(w2s + 8 * jg);
    float4 w2b = *(const float4*)(w2s + 8 * jg + 4);
    const float b1v[8] = {b1a.x, b1a.y, b1a.z, b1a.w, b1b.x, b1b.y, b1b.z, b1b.w};
    const float w2v[8] = {w2a.x, w2a.y, w2a.z, w2a.w, w2b.x, w2b.y, w2b.z, w2b.w};

    float lanesum = 0.f;
    #pragma unroll
    for (int i = 0; i < 4; i++) {
        int p = pb + i;                        // Lehmer parity
        int d0 = p / 24;  int r0 = p - 24 * d0;
        int d1 = r0 / 6;  int r1 = r0 - 6 * d1;
        int d2 = r1 >> 1; int d3 = r1 & 1;
        float sgn = ((d0 + d1 + d2 + d3) & 1) ? -1.f : 1.f;
        if (!pvalid) sgn = 0.f;
        float si = 0.f;
        #pragma unroll
        for (int r = 0; r < 8; r++)
            si = fmaf(fast_tanh(v[i][r] + b1v[r]), w2v[r], si);
        lanesum = fmaf(sgn, si, lanesum);
    }

    double dvj = (double)lanesum;
    #pragma unroll
    for (int off = 32; off > 0; off >>= 1) dvj += __shfl_down(dvj, off, 64);
    if (lane == 0) red_j[wave] = dvj;
    __syncthreads();
    if (t == 0)
        psum[s * B + b] = (float)((red_h[0] + red_h[1]) +
                                  ((red_j[0] + red_j[1]) + (red_j[2] + red_j[3])));
    // b2 omitted: sum_p sign_p = 0 kills it exactly.
}

// ---------------- combine: log|ps0*ps1| + jastrow (validated form) ----------------
__global__ void combine_kern(const float* __restrict__ psum,
                             const float* __restrict__ elec_pos,
                             const float* __restrict__ ion_pos,
                             const float* __restrict__ jk,
                             float* __restrict__ out, int B)
{
    int b = blockIdx.x * 256 + threadIdx.x;
    if (b >= B) return;
    const float i0x = ion_pos[0], i0y = ion_pos[1], i0z = ion_pos[2];
    const float i1x = ion_pos[3], i1y = ion_pos[4], i1z = ion_pos[5];
    const float j0 = jk[0], j1 = jk[1];
    const float* ep = elec_pos + b * NELEC * DIM;
    float jas = 0.f;
    #pragma unroll
    for (int e = 0; e < NELEC; e++) {
        float ex = ep[e * 3 + 0], ey = ep[e * 3 + 1], ez = ep[e * 3 + 2];
        float dx0 = ex - i0x, dy0 = ey - i0y, dz0 = ez - i0z;
        float dx1 = ex - i1x, dy1 = ey - i1y, dz1 = ez - i1z;
        jas += j0 * sqrtf(dx0 * dx0 + dy0 * dy0 + dz0 * dz0);
        jas += j1 * sqrtf(dx1 * dx1 + dy1 * dy1 + dz1 * dz1);
    }
    float ps0 = psum[b], ps1 = psum[B + b];
    out[b] = logf(fabsf(ps0 * ps1)) - jas;
}

extern "C" void kernel_launch(void* const* d_in, const int* in_sizes, int n_in,
                              void* d_out, int out_size, void* d_ws, size_t ws_size,
                              hipStream_t stream) {
    const float* elec_pos = (const float*)d_in[0];
    const float* ion_pos  = (const float*)d_in[1];
    const float* bf_w     = (const float*)d_in[2];
    const float* bf_b     = (const float*)d_in[3];
    const float* w0       = (const float*)d_in[4];
    const float* b0       = (const float*)d_in[5];
    const float* w1       = (const float*)d_in[6];
    const float* b1       = (const float*)d_in[7];
    const float* w2       = (const float*)d_in[8];
    const float* jk       = (const float*)d_in[10];
    float* out = (float*)d_out;

    const int B = in_sizes[0] / (NELEC * DIM);   // 2048

    float* psum = (float*)d_ws;                  // [2][B]

    hipLaunchKernelGGL(antisym_kern,
                       dim3(B, NSPIN), dim3(256), 0, stream,
                       elec_pos, ion_pos, bf_w, bf_b, w0, b0, w1, b1, w2, psum, B);
    hipLaunchKernelGGL(combine_kern,
                       dim3((B + 255) / 256), dim3(256), 0, stream,
                       psum, elec_pos, ion_pos, jk, out, B);
}

// Round 10
// 161.769 us; speedup vs baseline: 1.2257x; 1.2257x over previous
//
#include <hip/hip_runtime.h>
#include <math.h>

#define NELEC 10
#define NSPIN 2
#define NPER 5
#define DIM 3
#define NION 2
#define DP 32
#define NDENSE 64
#define NPERM 120
#define RS 324   // G row stride (words): rows at pool+160+324j -> start bank 4j -> the 5
                 // selectable rows hit disjoint bank quads; b128-aligned. 0 conflicts (R5-R9).
#define HTS 124  // HT row stride (words): phase-2 b128 reads at banks {8g%32} -> 2 addrs per
                 // bank-quad (free, m136); phase-1 b32 writes lane-consecutive -> 2/bank free.

// LDS pool with live-range overlay:
//   stage A (stages 1-2 + phase-1 reads): s1e[160] @ 0, G[5][324] @ 160..1780
//   stage B (phase-2):                    HT[64][124] @ 0..7936
// h is carried in REGISTERS across the A->B transition, so G can be overwritten.
// Total 31744 B (+64 B reductions) -> <=32768 -> 5 blocks/CU (was 38912 -> 4).
#define POOL_WORDS (NDENSE * HTS)

// tanh(x) = 1 - 2*rcp(exp(2x)+1): v_exp + v_rcp, ~1-2 ulp, exact at saturation. Validated R5-R9.
__device__ __forceinline__ float fast_tanh(float x) {
    float e = __expf(2.0f * x);
    return 1.0f - 2.0f * __builtin_amdgcn_rcpf(e + 1.0f);
}

__device__ __forceinline__ unsigned pick_remove(unsigned& el, int d) {
    unsigned v = (el >> (4 * d)) & 0xFu;
    unsigned low = el & ((1u << (4 * d)) - 1u);
    el = low | ((el >> (4 * (d + 1))) << (4 * d));
    return v;
}

// ---------------- main: one block per (batch, spin), 2 waves (R8-validated shape) ----------------
// R8 measured latency-bound (VALU 59%, occ 18% = 2 waves/SIMD, LDS-capped 4 blocks/CU).
// R9 (4-wave blocks) regressed: phase-1 half-idle + halved w1 reuse. This round keeps the
// R8 structure and attacks occupancy: G/HT LDS overlay (31.7 KB -> 5 blocks/CU) + explicit
// k+1 prefetch in the phase-2 GEMM.
__global__ __launch_bounds__(128, 1) void antisym_kern(
    const float* __restrict__ elec_pos, const float* __restrict__ ion_pos,
    const float* __restrict__ bf_w, const float* __restrict__ bf_b,
    const float* __restrict__ w0, const float* __restrict__ b0,
    const float* __restrict__ w1, const float* __restrict__ b1,
    const float* __restrict__ w2,
    float* __restrict__ psum, int B)
{
    const int b = blockIdx.x;
    const int s = blockIdx.y;
    const int t = threadIdx.x;
    const int wave = t >> 6, lane = t & 63;

    __shared__ __align__(16) float pool[POOL_WORDS];    // 31744 B, overlaid (see above)
    __shared__ double red_h[2];
    __shared__ double red_j[2];

    float* s1e = pool;                                  // [160]      (stage A)
    #define GROW(j) (pool + 160 + (j) * RS)             // G[j][·]    (stage A)
    #define HTROW(k) (pool + (k) * HTS)                 // HT[k][·]   (stage B)

    // ---- stage 1: stream_1e = tanh(feats @ bf_w + bf_b) for this spin's 5 electrons ----
    const float* ep = elec_pos + (b * NELEC + s * NPER) * DIM;
    const float i0x = ion_pos[0], i0y = ion_pos[1], i0z = ion_pos[2];
    const float i1x = ion_pos[3], i1y = ion_pos[4], i1z = ion_pos[5];
    for (int idx = t; idx < NPER * DP; idx += 128) {
        int j = idx >> 5, c = idx & 31;
        float ex = ep[j * 3 + 0], ey = ep[j * 3 + 1], ez = ep[j * 3 + 2];
        float dx0 = ex - i0x, dy0 = ey - i0y, dz0 = ez - i0z;
        float dx1 = ex - i1x, dy1 = ey - i1y, dz1 = ez - i1z;
        float n0 = sqrtf(dx0 * dx0 + dy0 * dy0 + dz0 * dz0);
        float n1 = sqrtf(dx1 * dx1 + dy1 * dy1 + dz1 * dz1);
        float acc = bf_b[c];
        acc += dx0 * bf_w[0 * DP + c];
        acc += dy0 * bf_w[1 * DP + c];
        acc += dz0 * bf_w[2 * DP + c];
        acc += dx1 * bf_w[3 * DP + c];
        acc += dy1 * bf_w[4 * DP + c];
        acc += dz1 * bf_w[5 * DP + c];
        acc += n0 * bf_w[6 * DP + c];
        acc += n1 * bf_w[7 * DP + c];
        s1e[idx] = fast_tanh(acc);
    }
    __syncthreads();

    // ---- stage 2: G[j][i*64+c] = s1e[j][:] @ w0[s][32i:32i+32, c] (R5-R9 validated) ----
    const float* w0s = w0 + s * (NPER * DP) * NDENSE;   // [160][64]
    for (int j = wave; j < NPER; j += 2) {
        float4 sv4[8];
        #pragma unroll
        for (int q = 0; q < 8; q++) sv4[q] = *(const float4*)(s1e + j * DP + q * 4);
        #pragma unroll
        for (int i = 0; i < NPER; i++) {
            float acc = 0.f;
            #pragma unroll
            for (int q = 0; q < 8; q++) {
                const float* wb = w0s + (i * DP + q * 4) * NDENSE + lane;  // coalesced
                acc += sv4[q].x * wb[0 * NDENSE];
                acc += sv4[q].y * wb[1 * NDENSE];
                acc += sv4[q].z * wb[2 * NDENSE];
                acc += sv4[q].w * wb[3 * NDENSE];
            }
            GROW(j)[i * NDENSE + lane] = acc;
        }
    }
    __syncthreads();

    const float* b0s = b0 + s * NDENSE;
    const float* w2s = w2 + s * NDENSE;     // w2 is [s][64][1]

    // ---- stage 3 phase 1: lane = perm. h_p built ENTIRELY in registers (G still live) ----
    const int pid = wave * 60 + lane;
    float sign = 0.f;
    int p0 = 0, p1 = 0, p2 = 0, p3 = 0, p4 = 0;
    if (lane < 60) {
        int p = pid;
        unsigned el = 0x43210u;
        int d0 = p / 24; p -= d0 * 24;
        int d1 = p / 6;  p -= d1 * 6;
        int d2 = p / 2;  p -= d2 * 2;
        int d3 = p;
        p0 = pick_remove(el, d0);
        p1 = pick_remove(el, d1);
        p2 = pick_remove(el, d2);
        p3 = pick_remove(el, d3);
        p4 = el & 0xF;
        sign = ((d0 + d1 + d2 + d3) & 1) ? -1.f : 1.f;
    }
    const float* g0 = GROW(p0) + 0 * NDENSE;
    const float* g1 = GROW(p1) + 1 * NDENSE;
    const float* g2 = GROW(p2) + 2 * NDENSE;
    const float* g3 = GROW(p3) + 3 * NDENSE;
    const float* g4 = GROW(p4) + 4 * NDENSE;

    float h[NDENSE];                        // constant-indexed -> VGPR-resident
    float hdot = 0.f;
    #pragma unroll
    for (int cc = 0; cc < NDENSE / 4; cc++) {
        float4 a = *(const float4*)(b0s + cc * 4);                    // uniform -> s_load
        float4 q;
        q = *(const float4*)(g0 + cc * 4); a.x += q.x; a.y += q.y; a.z += q.z; a.w += q.w;
        q = *(const float4*)(g1 + cc * 4); a.x += q.x; a.y += q.y; a.z += q.z; a.w += q.w;
        q = *(const float4*)(g2 + cc * 4); a.x += q.x; a.y += q.y; a.z += q.z; a.w += q.w;
        q = *(const float4*)(g3 + cc * 4); a.x += q.x; a.y += q.y; a.z += q.z; a.w += q.w;
        q = *(const float4*)(g4 + cc * 4); a.x += q.x; a.y += q.y; a.z += q.z; a.w += q.w;
        float t0 = fast_tanh(a.x), t1 = fast_tanh(a.y), t2 = fast_tanh(a.z), t3 = fast_tanh(a.w);
        h[cc * 4 + 0] = t0; h[cc * 4 + 1] = t1; h[cc * 4 + 2] = t2; h[cc * 4 + 3] = t3;
        hdot += t0 * w2s[cc * 4 + 0] + t1 * w2s[cc * 4 + 1]
              + t2 * w2s[cc * 4 + 2] + t3 * w2s[cc * 4 + 3];
    }

    double dvh = (double)(sign * hdot);     // sign=0 for lanes 60-63
    #pragma unroll
    for (int off = 32; off > 0; off >>= 1) dvh += __shfl_down(dvh, off, 64);
    if (lane == 0) red_h[wave] = dvh;

    __syncthreads();                        // ALL G reads complete -> pool reusable

    // park h transposed: HT[k][pid] (b32 writes, consecutive pids -> 2 lanes/bank = free)
    if (lane < 60) {
        #pragma unroll
        for (int k = 0; k < NDENSE; k++) HTROW(k)[pid] = h[k];
    }
    __syncthreads();                        // HT visible cross-wave

    // ---- stage 3 phase 2: 8x8 register-tiled GEMM V[120x64] = H @ W1, k+1 prefetch ----
    // wave0: perms 0..63 (pb=8*pg). wave1: perms 56..119; pg==0 duplicates 56-63 -> sgn 0.
    const int pg = lane >> 3, jg = lane & 7;
    const int pb = wave ? (56 + 8 * pg) : (8 * pg);
    const float* w1s = w1 + s * NDENSE * NDENSE;
    const float* b1s = b1 + s * NDENSE;
    const float* wgp = w1s + 8 * jg;        // this lane's j-octet in w1 row k

    float v[8][8];
    #pragma unroll
    for (int i = 0; i < 8; i++)
        #pragma unroll
        for (int r = 0; r < 8; r++) v[i][r] = 0.f;

    float4 ha_n = *(const float4*)(&HTROW(0)[pb]);
    float4 hb_n = *(const float4*)(&HTROW(0)[pb + 4]);
    float4 wa_n = *(const float4*)(wgp);
    float4 wb_n = *(const float4*)(wgp + 4);
    #pragma unroll 4
    for (int k = 0; k < NDENSE; k++) {
        const float4 ha = ha_n, hb = hb_n, wa = wa_n, wb = wb_n;
        if (k + 1 < NDENSE) {               // explicit k+1 prefetch (load->use distance)
            ha_n = *(const float4*)(&HTROW(k + 1)[pb]);
            hb_n = *(const float4*)(&HTROW(k + 1)[pb + 4]);
            wa_n = *(const float4*)(wgp + (k + 1) * NDENSE);
            wb_n = *(const float4*)(wgp + (k + 1) * NDENSE + 4);
        }
        const float hv[8] = {ha.x, ha.y, ha.z, ha.w, hb.x, hb.y, hb.z, hb.w};
        const float wv[8] = {wa.x, wa.y, wa.z, wa.w, wb.x, wb.y, wb.z, wb.w};
        #pragma unroll
        for (int i = 0; i < 8; i++)
            #pragma unroll
            for (int r = 0; r < 8; r++)
                v[i][r] = fmaf(hv[i], wv[r], v[i][r]);
    }

    // epilogue: lanesum = sum_i sgn_i * sum_r tanh(v[i][r]+b1[j]) * w2[j]
    float4 b1a = *(const float4*)(b1s + 8 * jg);
    float4 b1b = *(const float4*)(b1s + 8 * jg + 4);
    float4 w2a = *(const float4*)(w2s + 8 * jg);
    float4 w2b = *(const float4*)(w2s + 8 * jg + 4);
    const float b1v[8] = {b1a.x, b1a.y, b1a.z, b1a.w, b1b.x, b1b.y, b1b.z, b1b.w};
    const float w2v[8] = {w2a.x, w2a.y, w2a.z, w2a.w, w2b.x, w2b.y, w2b.z, w2b.w};

    float lanesum = 0.f;
    #pragma unroll
    for (int i = 0; i < 8; i++) {
        int p = pb + i;                      // Lehmer parity
        int d0 = p / 24;  int r0 = p - 24 * d0;
        int d1 = r0 / 6;  int r1 = r0 - 6 * d1;
        int d2 = r1 >> 1; int d3 = r1 & 1;
        float sgn = ((d0 + d1 + d2 + d3) & 1) ? -1.f : 1.f;
        if (wave == 1 && pg == 0) sgn = 0.f; // duplicate tile (perms 56-63)
        float si = 0.f;
        #pragma unroll
        for (int r = 0; r < 8; r++)
            si = fmaf(fast_tanh(v[i][r] + b1v[r]), w2v[r], si);
        lanesum = fmaf(sgn, si, lanesum);
    }

    double dvj = (double)lanesum;
    #pragma unroll
    for (int off = 32; off > 0; off >>= 1) dvj += __shfl_down(dvj, off, 64);
    if (lane == 0) red_j[wave] = dvj;
    __syncthreads();
    if (t == 0)
        psum[s * B + b] = (float)((red_h[0] + red_h[1]) + (red_j[0] + red_j[1]));
    // b2 omitted: sum_p sign_p = 0 kills it exactly.
}

// ---------------- combine: log|ps0*ps1| + jastrow (validated form) ----------------
__global__ void combine_kern(const float* __restrict__ psum,
                             const float* __restrict__ elec_pos,
                             const float* __restrict__ ion_pos,
                             const float* __restrict__ jk,
                             float* __restrict__ out, int B)
{
    int b = blockIdx.x * 256 + threadIdx.x;
    if (b >= B) return;
    const float i0x = ion_pos[0], i0y = ion_pos[1], i0z = ion_pos[2];
    const float i1x = ion_pos[3], i1y = ion_pos[4], i1z = ion_pos[5];
    const float j0 = jk[0], j1 = jk[1];
    const float* ep = elec_pos + b * NELEC * DIM;
    float jas = 0.f;
    #pragma unroll
    for (int e = 0; e < NELEC; e++) {
        float ex = ep[e * 3 + 0], ey = ep[e * 3 + 1], ez = ep[e * 3 + 2];
        float dx0 = ex - i0x, dy0 = ey - i0y, dz0 = ez - i0z;
        float dx1 = ex - i1x, dy1 = ey - i1y, dz1 = ez - i1z;
        jas += j0 * sqrtf(dx0 * dx0 + dy0 * dy0 + dz0 * dz0);
        jas += j1 * sqrtf(dx1 * dx1 + dy1 * dy1 + dz1 * dz1);
    }
    float ps0 = psum[b], ps1 = psum[B + b];
    out[b] = logf(fabsf(ps0 * ps1)) - jas;
}

extern "C" void kernel_launch(void* const* d_in, const int* in_sizes, int n_in,
                              void* d_out, int out_size, void* d_ws, size_t ws_size,
                              hipStream_t stream) {
    const float* elec_pos = (const float*)d_in[0];
    const float* ion_pos  = (const float*)d_in[1];
    const float* bf_w     = (const float*)d_in[2];
    const float* bf_b     = (const float*)d_in[3];
    const float* w0       = (const float*)d_in[4];
    const float* b0       = (const float*)d_in[5];
    const float* w1       = (const float*)d_in[6];
    const float* b1       = (const float*)d_in[7];
    const float* w2       = (const float*)d_in[8];
    const float* jk       = (const float*)d_in[10];
    float* out = (float*)d_out;

    const int B = in_sizes[0] / (NELEC * DIM);   // 2048

    float* psum = (float*)d_ws;                  // [2][B]

    hipLaunchKernelGGL(antisym_kern,
                       dim3(B, NSPIN), dim3(128), 0, stream,
                       elec_pos, ion_pos, bf_w, bf_b, w0, b0, w1, b1, w2, psum, B);
    hipLaunchKernelGGL(combine_kern,
                       dim3((B + 255) / 256), dim3(256), 0, stream,
                       psum, elec_pos, ion_pos, jk, out, B);
}